// Round 5
// baseline (1200.333 us; speedup 1.0000x reference)
//
#include <hip/hip_runtime.h>
#include <math.h>

#define D_   512
#define LAT_ 768
#define B_   16
#define S_   256
#define H_   8
#define DH_  64

typedef __bf16 bf16x8 __attribute__((ext_vector_type(8)));
typedef float f32x4 __attribute__((ext_vector_type(4)));

__device__ __forceinline__ unsigned short f2bf(float f) {
  unsigned u = __float_as_uint(f);
  unsigned r = (u + 0x7fffu + ((u >> 16) & 1u)) >> 16;
  return (unsigned short)r;
}

// ---------------- mask canonicalization (detect u8 / i32 / f32 storage) ------
__global__ void mask_canon_k(const void* __restrict__ mask, int* __restrict__ out, int n) {
  int i = blockIdx.x * blockDim.x + threadIdx.x;
  if (i >= n) return;
  const unsigned char* pb = (const unsigned char*)mask;
  const int*   pi = (const int*)mask;
  const float* pf = (const float*)mask;
  unsigned int w = ((const unsigned int*)mask)[1023];
  int v;
  if (w == 0x01010101u)      v = pb[i];
  else if (w == 0x3f800000u) v = (pf[i] != 0.0f);
  else                       v = (pi[i] != 0);
  out[i] = v ? 1 : 0;
}

// ---------------- segment starts (graph_batch is sorted) ---------------------
__global__ void starts_k(const int* __restrict__ gb, int* __restrict__ starts, int n) {
  int i = blockIdx.x * blockDim.x + threadIdx.x;
  if (i >= n) return;
  if (i == 0 || gb[i] != gb[i - 1]) starts[gb[i]] = i;
}

// ---------------- scatter ragged nodes -> dense [B,Lmax,D] -------------------
__global__ __launch_bounds__(256) void scatter_k(const float* __restrict__ nodes,
    const int* __restrict__ gb, const int* __restrict__ starts,
    float* __restrict__ dense, int Lmax) {
  int i = blockIdx.x;
  int b = gb[i], p = i - starts[b];
  const float* src = nodes + (size_t)i * D_;
  float* dst = dense + ((size_t)b * Lmax + p) * D_;
  dst[threadIdx.x]       = src[threadIdx.x];
  dst[threadIdx.x + 256] = src[threadIdx.x + 256];
}

// ---------------- pack B (fp32 [K][512]) -> MFMA chunk layout bf16 -----------
__global__ __launch_bounds__(256) void pack_b_k(const float* __restrict__ W,
    unsigned short* __restrict__ out, int K) {
  int idx = blockIdx.x * 256 + threadIdx.x;     // chunk id = kc*512 + n
  int n = idx & 511, kc = idx >> 9;
  int kt = kc >> 2, kblk = kc & 3;
  int nt = n >> 7, nblk = (n >> 4) & 7, col = n & 15;
  size_t ob = ((size_t)(nt * (K >> 5) + kt) * 4096) + nblk * 512 + kblk * 128 + col * 8;
  unsigned short v[8];
#pragma unroll
  for (int j = 0; j < 8; ++j) v[j] = f2bf(W[(size_t)(kc * 8 + j) * 512 + n]);
  int4 pk;
  pk.x = v[0] | (v[1] << 16); pk.y = v[2] | (v[3] << 16);
  pk.z = v[4] | (v[5] << 16); pk.w = v[6] | (v[7] << 16);
  *(int4*)&out[ob] = pk;
}

// ---------------- bf16 MFMA GEMM: C = A[MxK](f32) @ Bpk + bias ---------------
__global__ __launch_bounds__(256) void mgemm_k(const float* __restrict__ A,
    const unsigned short* __restrict__ Bpk, const float* __restrict__ bias,
    float* __restrict__ C, int M, int N, int K) {
  __shared__ __align__(16) unsigned short Al[4096];
  __shared__ __align__(16) unsigned short Bl[4096];
  const int tid = threadIdx.x;
  const int lane = tid & 63, wid = tid >> 6;
  const int wr = wid >> 1, wc = wid & 1;
  const int row0 = blockIdx.y * 128, col0 = blockIdx.x * 128;
  const int KT = K >> 5;
  f32x4 acc[4][4];
#pragma unroll
  for (int m = 0; m < 4; ++m)
#pragma unroll
    for (int n = 0; n < 4; ++n) acc[m][n] = (f32x4){0.f, 0.f, 0.f, 0.f};

  const int kb0 = tid & 3, ar0 = tid >> 2;
  const unsigned short* bsrc = Bpk + (size_t)blockIdx.x * KT * 4096;

  for (int kt = 0; kt < KT; ++kt) {
    {
      const unsigned short* g1 = bsrc + (size_t)kt * 4096 + wid * 512 + lane * 8;
      __builtin_amdgcn_global_load_lds(
          (const __attribute__((address_space(1))) void*)g1,
          (__attribute__((address_space(3))) void*)&Bl[wid * 512], 16, 0, 0);
      __builtin_amdgcn_global_load_lds(
          (const __attribute__((address_space(1))) void*)(g1 + 2048),
          (__attribute__((address_space(3))) void*)&Bl[2048 + wid * 512], 16, 0, 0);
    }
#pragma unroll
    for (int cc = 0; cc < 2; ++cc) {
      int row = ar0 + cc * 64;
      const float* ap = A + (size_t)(row0 + row) * K + kt * 32 + kb0 * 8;
      float4 f0 = *(const float4*)ap;
      float4 f1 = *(const float4*)(ap + 4);
      int4 pk;
      pk.x = f2bf(f0.x) | (f2bf(f0.y) << 16);
      pk.y = f2bf(f0.z) | (f2bf(f0.w) << 16);
      pk.z = f2bf(f1.x) | (f2bf(f1.y) << 16);
      pk.w = f2bf(f1.z) | (f2bf(f1.w) << 16);
      *(int4*)&Al[(row >> 4) * 512 + kb0 * 128 + (row & 15) * 8] = pk;
    }
    __syncthreads();
    bf16x8 af[4], bfr[4];
#pragma unroll
    for (int m = 0; m < 4; ++m)
      af[m] = *(const bf16x8*)&Al[(wr * 4 + m) * 512 + lane * 8];
#pragma unroll
    for (int n = 0; n < 4; ++n)
      bfr[n] = *(const bf16x8*)&Bl[(wc * 4 + n) * 512 + lane * 8];
#pragma unroll
    for (int m = 0; m < 4; ++m)
#pragma unroll
      for (int n = 0; n < 4; ++n)
        acc[m][n] = __builtin_amdgcn_mfma_f32_16x16x32_bf16(af[m], bfr[n], acc[m][n], 0, 0, 0);
    __syncthreads();
  }
  const int cl = lane & 15, rg = lane >> 4;
  float bv[4];
#pragma unroll
  for (int n = 0; n < 4; ++n)
    bv[n] = bias ? bias[col0 + wc * 64 + n * 16 + cl] : 0.f;
#pragma unroll
  for (int m = 0; m < 4; ++m) {
    int r = row0 + wr * 64 + m * 16 + rg * 4;
#pragma unroll
    for (int n = 0; n < 4; ++n) {
      int c = col0 + wc * 64 + n * 16 + cl;
#pragma unroll
      for (int i = 0; i < 4; ++i)
        C[(size_t)(r + i) * N + c] = acc[m][n][i] + bv[n];
    }
  }
}

// ---------------- fold bias through in-projection: out = bin@W + badd --------
__global__ void bias_comb_k(const float* __restrict__ bin, const float* __restrict__ W,
    const float* __restrict__ badd, float* __restrict__ out) {
  int j = blockIdx.x * 256 + threadIdx.x;
  float s = badd[j];
  for (int k = 0; k < D_; ++k) s += bin[k] * W[(size_t)k * D_ + j];
  out[j] = s;
}

// ---------------- per-head tiled attention: 32 q-rows x 1 head per block -----
// grid (Lmax/32, B, H). 256 threads; thread -> (r=tid>>3, c=tid&7).
// avout must be pre-zeroed; each block atomicAdds its head's weights / H.
__global__ __launch_bounds__(256) void attn_k(const float* __restrict__ qh,
    const float* __restrict__ kh, const float* __restrict__ vh,
    const int* __restrict__ maskc, float* __restrict__ ctx,
    float* __restrict__ avout, int Lmax) {
  const int b = blockIdx.y, h = blockIdx.z;
  const int l0 = blockIdx.x * 32;
  const int tid = threadIdx.x;
  const int r = tid >> 3, c = tid & 7;
  const int lrow = tid >> 2, lcb = (tid & 3) * 16;
  __shared__ float qa[32][68];      // Q during QK^T; attn weights during PV
  __shared__ float kv[64][68];      // K chunk transposed [d][s]; V chunk [s][d]
  __shared__ int   mask_s[S_];
  mask_s[tid] = maskc[b * S_ + tid];
  const size_t qbase = (size_t)b * Lmax + l0;

  // ---- load Q tile [32][64] (this head) ----
  {
    const float4* qs = (const float4*)(qh + (qbase + r) * D_ + h * DH_ + c * 8);
    float4 v0 = qs[0], v1 = qs[1];
    *(float4*)&qa[r][c * 8]     = v0;
    *(float4*)&qa[r][c * 8 + 4] = v1;
  }
  float sc[4][8];
  // ---- QK^T: 4 chunks of 64 s ----
#pragma unroll
  for (int m = 0; m < 4; ++m) {
    __syncthreads();
    const float4* ks = (const float4*)(kh +
        ((size_t)(b * S_ + m * 64 + lrow)) * D_ + h * DH_ + lcb);
#pragma unroll
    for (int i = 0; i < 4; ++i) {
      float4 t = ks[i];
      kv[lcb + i * 4 + 0][lrow] = t.x;
      kv[lcb + i * 4 + 1][lrow] = t.y;
      kv[lcb + i * 4 + 2][lrow] = t.z;
      kv[lcb + i * 4 + 3][lrow] = t.w;
    }
    __syncthreads();
    float a0 = 0.f, a1 = 0.f, a2 = 0.f, a3 = 0.f;
    float a4 = 0.f, a5 = 0.f, a6 = 0.f, a7 = 0.f;
#pragma unroll 16
    for (int d = 0; d < 64; ++d) {
      float qv = qa[r][d];
      const float* kp = &kv[d][c * 8];
      a0 += qv * kp[0]; a1 += qv * kp[1]; a2 += qv * kp[2]; a3 += qv * kp[3];
      a4 += qv * kp[4]; a5 += qv * kp[5]; a6 += qv * kp[6]; a7 += qv * kp[7];
    }
    sc[m][0] = a0; sc[m][1] = a1; sc[m][2] = a2; sc[m][3] = a3;
    sc[m][4] = a4; sc[m][5] = a5; sc[m][6] = a6; sc[m][7] = a7;
  }
  // ---- softmax over the full row via 8-lane shfl group ----
  float mx = -3.0e38f;
#pragma unroll
  for (int m = 0; m < 4; ++m)
#pragma unroll
    for (int j = 0; j < 8; ++j) {
      float v = sc[m][j] * 0.125f;
      if (mask_s[m * 64 + c * 8 + j]) v = -1.0e30f;
      sc[m][j] = v;
      mx = fmaxf(mx, v);
    }
  mx = fmaxf(mx, __shfl_xor(mx, 1));
  mx = fmaxf(mx, __shfl_xor(mx, 2));
  mx = fmaxf(mx, __shfl_xor(mx, 4));
  float sum = 0.f;
#pragma unroll
  for (int m = 0; m < 4; ++m)
#pragma unroll
    for (int j = 0; j < 8; ++j) {
      float e = __expf(sc[m][j] - mx);
      sc[m][j] = e;
      sum += e;
    }
  sum += __shfl_xor(sum, 1);
  sum += __shfl_xor(sum, 2);
  sum += __shfl_xor(sum, 4);
  float inv = 1.f / sum;
#pragma unroll
  for (int m = 0; m < 4; ++m)
#pragma unroll
    for (int j = 0; j < 8; ++j) sc[m][j] *= inv;
  // ---- PV: ctx[r][c*8+j] = sum_s a[r][s] * V[s][c*8+j] ----
  float cacc[8];
#pragma unroll
  for (int j = 0; j < 8; ++j) cacc[j] = 0.f;
#pragma unroll
  for (int m = 0; m < 4; ++m) {
    __syncthreads();   // guards kv AND qa rewrite (Q dead after QK)
    const float4* vs = (const float4*)(vh +
        ((size_t)(b * S_ + m * 64 + lrow)) * D_ + h * DH_ + lcb);
#pragma unroll
    for (int i = 0; i < 4; ++i)
      *(float4*)&kv[lrow][lcb + i * 4] = vs[i];
    *(float4*)&qa[r][c * 8]     = make_float4(sc[m][0], sc[m][1], sc[m][2], sc[m][3]);
    *(float4*)&qa[r][c * 8 + 4] = make_float4(sc[m][4], sc[m][5], sc[m][6], sc[m][7]);
    __syncthreads();
#pragma unroll 8
    for (int sl = 0; sl < 64; ++sl) {
      float a = qa[r][sl];
      const float* vp = &kv[sl][c * 8];
#pragma unroll
      for (int j = 0; j < 8; ++j) cacc[j] += a * vp[j];
    }
  }
  float* cp = ctx + (qbase + r) * D_ + h * DH_ + c * 8;
  *(float4*)cp       = make_float4(cacc[0], cacc[1], cacc[2], cacc[3]);
  *(float4*)(cp + 4) = make_float4(cacc[4], cacc[5], cacc[6], cacc[7]);
  // ---- head-averaged weights: atomic accumulate (avout pre-zeroed) ----
#pragma unroll
  for (int m = 0; m < 4; ++m) {
    float* ap = avout + (qbase + r) * S_ + m * 64 + c * 8;
#pragma unroll
    for (int j = 0; j < 8; ++j)
      atomicAdd(ap + j, sc[m][j] * 0.125f);
  }
}

// ---------------- x1 = LN(a + r) --------------------------------------------
__global__ __launch_bounds__(256) void ln_add_k(const float* __restrict__ a,
    const float* __restrict__ r, const float* __restrict__ g,
    const float* __restrict__ be, float* __restrict__ out) {
  size_t row = (size_t)blockIdx.x * D_;
  int tid = threadIdx.x;
  __shared__ float red[256];
  float v0 = a[row + tid]       + r[row + tid];
  float v1 = a[row + tid + 256] + r[row + tid + 256];
  red[tid] = v0 + v1;
  __syncthreads();
  for (int o = 128; o > 0; o >>= 1) { if (tid < o) red[tid] += red[tid + o]; __syncthreads(); }
  float mean = red[0] * (1.f / D_);
  __syncthreads();
  red[tid] = v0 * v0 + v1 * v1;
  __syncthreads();
  for (int o = 128; o > 0; o >>= 1) { if (tid < o) red[tid] += red[tid + o]; __syncthreads(); }
  float var = red[0] * (1.f / D_) - mean * mean;
  float rstd = rsqrtf(var + 1e-5f);
  out[row + tid]       = (v0 - mean) * rstd * g[tid]       + be[tid];
  out[row + tid + 256] = (v1 - mean) * rstd * g[tid + 256] + be[tid + 256];
}

// ---------------- out[i] = LN(leaky(h1)+x1) gathered to ragged rows ----------
__global__ __launch_bounds__(256) void final_k(const float* __restrict__ h1,
    const float* __restrict__ x1, const int* __restrict__ gb,
    const int* __restrict__ starts, const float* __restrict__ g,
    const float* __restrict__ be, float* __restrict__ out, int Lmax) {
  int i = blockIdx.x, tid = threadIdx.x;
  int b = gb[i], p = i - starts[b];
  size_t row = ((size_t)b * Lmax + p) * D_;
  __shared__ float red[256];
  float t0 = h1[row + tid];       t0 = (t0 >= 0.f) ? t0 : 0.01f * t0; t0 += x1[row + tid];
  float t1 = h1[row + tid + 256]; t1 = (t1 >= 0.f) ? t1 : 0.01f * t1; t1 += x1[row + tid + 256];
  red[tid] = t0 + t1;
  __syncthreads();
  for (int o = 128; o > 0; o >>= 1) { if (tid < o) red[tid] += red[tid + o]; __syncthreads(); }
  float mean = red[0] * (1.f / D_);
  __syncthreads();
  red[tid] = t0 * t0 + t1 * t1;
  __syncthreads();
  for (int o = 128; o > 0; o >>= 1) { if (tid < o) red[tid] += red[tid + o]; __syncthreads(); }
  float var = red[0] * (1.f / D_) - mean * mean;
  float rstd = rsqrtf(var + 1e-5f);
  out[(size_t)i * D_ + tid]       = (t0 - mean) * rstd * g[tid]       + be[tid];
  out[(size_t)i * D_ + tid + 256] = (t1 - mean) * rstd * g[tid + 256] + be[tid + 256];
}

// ---------------- host launcher ----------------------------------------------
extern "C" void kernel_launch(void* const* d_in, const int* in_sizes, int n_in,
                              void* d_out, int out_size, void* d_ws, size_t ws_size,
                              hipStream_t stream) {
  const float* nodes = (const float*)d_in[0];
  const int*   gb    = (const int*)d_in[1];
  const float* cond  = (const float*)d_in[2];
  const void*  maskp = d_in[3];
  const float* Wq   = (const float*)d_in[6];
  const float* bq   = (const float*)d_in[7];
  const float* Wk   = (const float*)d_in[8];
  const float* bk   = (const float*)d_in[9];
  const float* Wv   = (const float*)d_in[10];
  const float* bv   = (const float*)d_in[11];
  const float* in_w = (const float*)d_in[12];
  const float* in_b = (const float*)d_in[13];
  const float* Wo   = (const float*)d_in[14];
  const float* bo   = (const float*)d_in[15];
  const float* g1   = (const float*)d_in[16];
  const float* b1ln = (const float*)d_in[17];
  const float* W1   = (const float*)d_in[18];
  const float* b1f  = (const float*)d_in[19];
  const float* g2   = (const float*)d_in[20];
  const float* b2ln = (const float*)d_in[21];

  const int N    = in_sizes[0] / D_;                    // 12032
  const int Lmax = (out_size - N * D_) / (B_ * S_);     // 992
  const int BL   = B_ * Lmax;                           // 15872

  float* ws = (float*)d_ws;
  int* starts = (int*)(ws + 0);
  int* maskc  = (int*)(ws + 64);
  size_t o = 8192;
  float* dense = ws + o; o += (size_t)BL * D_;
  float* qh    = ws + o; o += (size_t)BL * D_;
  float* ctx   = qh;              // alias safe: block reads its Q head-slice before writing same ctx slice
  float* kh    = ws + o; o += (size_t)B_ * S_ * D_;
  float* vh    = ws + o; o += (size_t)B_ * S_ * D_;
  float* tmp   = ws + o; o += (size_t)BL * D_;
  float* x1    = ws + o; o += (size_t)BL * D_;
  float* h1    = dense;           // alias: dense dead after ln_add_k
  float* Wqp = ws + o; o += (size_t)D_ * D_;
  float* Wkp = ws + o; o += (size_t)LAT_ * D_;
  float* Wvp = ws + o; o += (size_t)LAT_ * D_;
  float* bqp = ws + o; o += D_;
  float* bkp = ws + o; o += D_;
  float* bvp = ws + o; o += D_;
  unsigned short* iw0_pk = (unsigned short*)(ws + o); o += (size_t)D_ * D_ / 2;
  unsigned short* iw1_pk = (unsigned short*)(ws + o); o += (size_t)D_ * D_ / 2;
  unsigned short* iw2_pk = (unsigned short*)(ws + o); o += (size_t)D_ * D_ / 2;
  unsigned short* Wqp_pk = (unsigned short*)(ws + o); o += (size_t)D_ * D_ / 2;
  unsigned short* Wkp_pk = (unsigned short*)(ws + o); o += (size_t)LAT_ * D_ / 2;
  unsigned short* Wvp_pk = (unsigned short*)(ws + o); o += (size_t)LAT_ * D_ / 2;
  unsigned short* Wo_pk  = (unsigned short*)(ws + o); o += (size_t)D_ * D_ / 2;
  unsigned short* W1_pk  = (unsigned short*)(ws + o); o += (size_t)D_ * D_ / 2;

  (void)hipMemsetAsync(d_ws, 0, (8192 + (size_t)BL * D_) * sizeof(float), stream);
  // zero av_attn region: attn_k accumulates into it atomically every call
  (void)hipMemsetAsync((float*)d_out + (size_t)N * D_, 0,
                       (size_t)BL * S_ * sizeof(float), stream);

  mask_canon_k<<<(B_ * S_ + 255) / 256, 256, 0, stream>>>(maskp, maskc, B_ * S_);
  starts_k<<<(N + 255) / 256, 256, 0, stream>>>(gb, starts, N);
  scatter_k<<<N, 256, 0, stream>>>(nodes, gb, starts, dense, Lmax);

  pack_b_k<<<(D_ / 8) * 512 / 256, 256, 0, stream>>>(in_w,              iw0_pk, D_);
  pack_b_k<<<(D_ / 8) * 512 / 256, 256, 0, stream>>>(in_w + D_ * D_,    iw1_pk, D_);
  pack_b_k<<<(D_ / 8) * 512 / 256, 256, 0, stream>>>(in_w + 2 * D_ * D_, iw2_pk, D_);
  pack_b_k<<<(D_ / 8) * 512 / 256, 256, 0, stream>>>(Wo, Wo_pk, D_);
  pack_b_k<<<(D_ / 8) * 512 / 256, 256, 0, stream>>>(W1, W1_pk, D_);

  mgemm_k<<<dim3(4, D_ / 128), 256, 0, stream>>>(Wq, iw0_pk, nullptr, Wqp, D_, D_, D_);
  mgemm_k<<<dim3(4, LAT_ / 128), 256, 0, stream>>>(Wk, iw1_pk, nullptr, Wkp, LAT_, D_, D_);
  mgemm_k<<<dim3(4, LAT_ / 128), 256, 0, stream>>>(Wv, iw2_pk, nullptr, Wvp, LAT_, D_, D_);
  pack_b_k<<<(D_ / 8) * 512 / 256, 256, 0, stream>>>(Wqp, Wqp_pk, D_);
  pack_b_k<<<(LAT_ / 8) * 512 / 256, 256, 0, stream>>>(Wkp, Wkp_pk, LAT_);
  pack_b_k<<<(LAT_ / 8) * 512 / 256, 256, 0, stream>>>(Wvp, Wvp_pk, LAT_);
  bias_comb_k<<<2, 256, 0, stream>>>(bq, in_w,               in_b,          bqp);
  bias_comb_k<<<2, 256, 0, stream>>>(bk, in_w + D_ * D_,     in_b + D_,     bkp);
  bias_comb_k<<<2, 256, 0, stream>>>(bv, in_w + 2 * D_ * D_, in_b + 2 * D_, bvp);

  mgemm_k<<<dim3(4, BL / 128), 256, 0, stream>>>(dense, Wqp_pk, bqp, qh, BL, D_, D_);
  mgemm_k<<<dim3(4, (B_ * S_) / 128), 256, 0, stream>>>(cond, Wkp_pk, bkp, kh, B_ * S_, D_, LAT_);
  mgemm_k<<<dim3(4, (B_ * S_) / 128), 256, 0, stream>>>(cond, Wvp_pk, bvp, vh, B_ * S_, D_, LAT_);

  attn_k<<<dim3(Lmax / 32, B_, H_), 256, 0, stream>>>(qh, kh, vh, maskc, ctx,
      (float*)d_out + (size_t)N * D_, Lmax);

  mgemm_k<<<dim3(4, BL / 128), 256, 0, stream>>>(ctx, Wo_pk, bo, tmp, BL, D_, D_);
  ln_add_k<<<BL, 256, 0, stream>>>(tmp, dense, g1, b1ln, x1);

  mgemm_k<<<dim3(4, BL / 128), 256, 0, stream>>>(x1, W1_pk, b1f, h1, BL, D_, D_);
  final_k<<<N, 256, 0, stream>>>(h1, x1, gb, starts, g2, b2ln, (float*)d_out, Lmax);
}

// Round 6
// 384.763 us; speedup vs baseline: 3.1197x; 3.1197x over previous
//
#include <hip/hip_runtime.h>
#include <math.h>

#define D_   512
#define LAT_ 768
#define B_   16
#define S_   256
#define H_   8
#define DH_  64

typedef __bf16 bf16x8 __attribute__((ext_vector_type(8)));
typedef float f32x4 __attribute__((ext_vector_type(4)));

__device__ __forceinline__ unsigned short f2bf(float f) {
  unsigned u = __float_as_uint(f);
  unsigned r = (u + 0x7fffu + ((u >> 16) & 1u)) >> 16;
  return (unsigned short)r;
}

// ---------------- mask canonicalization (detect u8 / i32 / f32 storage) ------
__global__ void mask_canon_k(const void* __restrict__ mask, int* __restrict__ out, int n) {
  int i = blockIdx.x * blockDim.x + threadIdx.x;
  if (i >= n) return;
  const unsigned char* pb = (const unsigned char*)mask;
  const int*   pi = (const int*)mask;
  const float* pf = (const float*)mask;
  unsigned int w = ((const unsigned int*)mask)[1023];
  int v;
  if (w == 0x01010101u)      v = pb[i];
  else if (w == 0x3f800000u) v = (pf[i] != 0.0f);
  else                       v = (pi[i] != 0);
  out[i] = v ? 1 : 0;
}

// ---------------- segment starts (graph_batch is sorted) ---------------------
__global__ void starts_k(const int* __restrict__ gb, int* __restrict__ starts, int n) {
  int i = blockIdx.x * blockDim.x + threadIdx.x;
  if (i >= n) return;
  if (i == 0 || gb[i] != gb[i - 1]) starts[gb[i]] = i;
}

// ---------------- scatter ragged nodes -> dense [B,Lmax,D] -------------------
__global__ __launch_bounds__(256) void scatter_k(const float* __restrict__ nodes,
    const int* __restrict__ gb, const int* __restrict__ starts,
    float* __restrict__ dense, int Lmax) {
  int i = blockIdx.x;
  int b = gb[i], p = i - starts[b];
  const float* src = nodes + (size_t)i * D_;
  float* dst = dense + ((size_t)b * Lmax + p) * D_;
  dst[threadIdx.x]       = src[threadIdx.x];
  dst[threadIdx.x + 256] = src[threadIdx.x + 256];
}

// ---------------- pack B (fp32 [K][512]) -> MFMA chunk layout bf16 -----------
__global__ __launch_bounds__(256) void pack_b_k(const float* __restrict__ W,
    unsigned short* __restrict__ out, int K) {
  int idx = blockIdx.x * 256 + threadIdx.x;     // chunk id = kc*512 + n
  int n = idx & 511, kc = idx >> 9;
  int kt = kc >> 2, kblk = kc & 3;
  int nt = n >> 7, nblk = (n >> 4) & 7, col = n & 15;
  size_t ob = ((size_t)(nt * (K >> 5) + kt) * 4096) + nblk * 512 + kblk * 128 + col * 8;
  unsigned short v[8];
#pragma unroll
  for (int j = 0; j < 8; ++j) v[j] = f2bf(W[(size_t)(kc * 8 + j) * 512 + n]);
  int4 pk;
  pk.x = v[0] | (v[1] << 16); pk.y = v[2] | (v[3] << 16);
  pk.z = v[4] | (v[5] << 16); pk.w = v[6] | (v[7] << 16);
  *(int4*)&out[ob] = pk;
}

// ---------------- bf16 MFMA GEMM: C = A[MxK](f32) @ Bpk + bias ---------------
__global__ __launch_bounds__(256) void mgemm_k(const float* __restrict__ A,
    const unsigned short* __restrict__ Bpk, const float* __restrict__ bias,
    float* __restrict__ C, int M, int N, int K) {
  __shared__ __align__(16) unsigned short Al[4096];
  __shared__ __align__(16) unsigned short Bl[4096];
  const int tid = threadIdx.x;
  const int lane = tid & 63, wid = tid >> 6;
  const int wr = wid >> 1, wc = wid & 1;
  const int row0 = blockIdx.y * 128, col0 = blockIdx.x * 128;
  const int KT = K >> 5;
  f32x4 acc[4][4];
#pragma unroll
  for (int m = 0; m < 4; ++m)
#pragma unroll
    for (int n = 0; n < 4; ++n) acc[m][n] = (f32x4){0.f, 0.f, 0.f, 0.f};

  const int kb0 = tid & 3, ar0 = tid >> 2;
  const unsigned short* bsrc = Bpk + (size_t)blockIdx.x * KT * 4096;

  for (int kt = 0; kt < KT; ++kt) {
    {
      const unsigned short* g1 = bsrc + (size_t)kt * 4096 + wid * 512 + lane * 8;
      __builtin_amdgcn_global_load_lds(
          (const __attribute__((address_space(1))) void*)g1,
          (__attribute__((address_space(3))) void*)&Bl[wid * 512], 16, 0, 0);
      __builtin_amdgcn_global_load_lds(
          (const __attribute__((address_space(1))) void*)(g1 + 2048),
          (__attribute__((address_space(3))) void*)&Bl[2048 + wid * 512], 16, 0, 0);
    }
#pragma unroll
    for (int cc = 0; cc < 2; ++cc) {
      int row = ar0 + cc * 64;
      const float* ap = A + (size_t)(row0 + row) * K + kt * 32 + kb0 * 8;
      float4 f0 = *(const float4*)ap;
      float4 f1 = *(const float4*)(ap + 4);
      int4 pk;
      pk.x = f2bf(f0.x) | (f2bf(f0.y) << 16);
      pk.y = f2bf(f0.z) | (f2bf(f0.w) << 16);
      pk.z = f2bf(f1.x) | (f2bf(f1.y) << 16);
      pk.w = f2bf(f1.z) | (f2bf(f1.w) << 16);
      *(int4*)&Al[(row >> 4) * 512 + kb0 * 128 + (row & 15) * 8] = pk;
    }
    __syncthreads();
    bf16x8 af[4], bfr[4];
#pragma unroll
    for (int m = 0; m < 4; ++m)
      af[m] = *(const bf16x8*)&Al[(wr * 4 + m) * 512 + lane * 8];
#pragma unroll
    for (int n = 0; n < 4; ++n)
      bfr[n] = *(const bf16x8*)&Bl[(wc * 4 + n) * 512 + lane * 8];
#pragma unroll
    for (int m = 0; m < 4; ++m)
#pragma unroll
      for (int n = 0; n < 4; ++n)
        acc[m][n] = __builtin_amdgcn_mfma_f32_16x16x32_bf16(af[m], bfr[n], acc[m][n], 0, 0, 0);
    __syncthreads();
  }
  const int cl = lane & 15, rg = lane >> 4;
  float bv[4];
#pragma unroll
  for (int n = 0; n < 4; ++n)
    bv[n] = bias ? bias[col0 + wc * 64 + n * 16 + cl] : 0.f;
#pragma unroll
  for (int m = 0; m < 4; ++m) {
    int r = row0 + wr * 64 + m * 16 + rg * 4;
#pragma unroll
    for (int n = 0; n < 4; ++n) {
      int c = col0 + wc * 64 + n * 16 + cl;
#pragma unroll
      for (int i = 0; i < 4; ++i)
        C[(size_t)(r + i) * N + c] = acc[m][n][i] + bv[n];
    }
  }
}

// ---------------- fold bias through in-projection: out = bin@W + badd --------
__global__ void bias_comb_k(const float* __restrict__ bin, const float* __restrict__ W,
    const float* __restrict__ badd, float* __restrict__ out) {
  int j = blockIdx.x * 256 + threadIdx.x;
  float s = badd[j];
  for (int k = 0; k < D_; ++k) s += bin[k] * W[(size_t)k * D_ + j];
  out[j] = s;
}

// ---------------- MFMA attention: 32 q-rows x all heads per block ------------
// 256 thr = 4 waves; wave w owns s-range w*64 (QK) and d-range w*16 (PV).
// Fragment layouts as verified in mgemm_k: A row=lane&15,k=(lane>>4)*8+j;
// B col=lane&15; C col=lane&15,row=(lane>>4)*4+i.
// grid: 1D, id = ltile*16 + b  (id%8 == b%8 -> per-XCD L2 holds 2 batches' K/V)
__device__ __forceinline__ float rmax16(float v) {
  v = fmaxf(v, __shfl_xor(v, 1)); v = fmaxf(v, __shfl_xor(v, 2));
  v = fmaxf(v, __shfl_xor(v, 4)); v = fmaxf(v, __shfl_xor(v, 8));
  return v;
}
__device__ __forceinline__ float rsum16(float v) {
  v += __shfl_xor(v, 1); v += __shfl_xor(v, 2);
  v += __shfl_xor(v, 4); v += __shfl_xor(v, 8);
  return v;
}

__global__ __launch_bounds__(256) void attn_k(const float* __restrict__ qh,
    const float* __restrict__ kh, const float* __restrict__ vh,
    const int* __restrict__ maskc, float* __restrict__ ctx,
    float* __restrict__ avout, int Lmax) {
  const int bid = blockIdx.x;
  const int b = bid & 15;
  const int l0 = (bid >> 4) * 32;
  const int tid = threadIdx.x;
  const int lane = tid & 63, w = tid >> 6;
  const int lg = lane >> 4, l15 = lane & 15;
  __shared__ __align__(16) __bf16 v_lds[256][72];   // V[s][d] bf16, row 144B
  __shared__ __align__(16) __bf16 p_lds[32][264];   // P[q][s] bf16, row 528B
  __shared__ float maxred[4][32];
  __shared__ float sumred[4][32];
  __shared__ float mask_s[S_];
  mask_s[tid] = maskc[b * S_ + tid] ? -1.0e30f : 0.f;
  __syncthreads();
  float madd[4];
#pragma unroll
  for (int n = 0; n < 4; ++n) madd[n] = mask_s[w * 64 + n * 16 + l15];

  float av[2][4][4];
#pragma unroll
  for (int m = 0; m < 2; ++m)
#pragma unroll
    for (int n = 0; n < 4; ++n)
#pragma unroll
      for (int i = 0; i < 4; ++i) av[m][n][i] = 0.f;

  const size_t qrow0 = (size_t)b * Lmax + l0;
  const int srow = tid >> 2, scol = (tid & 3) * 16;   // V staging map

#pragma unroll 1
  for (int h = 0; h < H_; ++h) {
    __syncthreads();   // prev head's PV reads done before restaging
    // ---- stage V[s][h*64..] -> v_lds bf16 (coalesced reads, b128 writes) ----
#pragma unroll
    for (int pass = 0; pass < 4; ++pass) {
      int s = pass * 64 + srow;
      const float* vp = vh + ((size_t)(b * S_ + s)) * D_ + h * DH_ + scol;
      bf16x8 t0, t1;
#pragma unroll
      for (int j = 0; j < 8; ++j) { t0[j] = (__bf16)vp[j]; t1[j] = (__bf16)vp[8 + j]; }
      *(bf16x8*)&v_lds[s][scol]     = t0;
      *(bf16x8*)&v_lds[s][scol + 8] = t1;
    }
    // ---- QK^T: fragments direct from global, 16 MFMA ----
    f32x4 qk[2][4];
#pragma unroll
    for (int m = 0; m < 2; ++m)
#pragma unroll
      for (int n = 0; n < 4; ++n) qk[m][n] = (f32x4){0.f, 0.f, 0.f, 0.f};
#pragma unroll
    for (int kt = 0; kt < 2; ++kt) {
      bf16x8 afr[2];
#pragma unroll
      for (int m = 0; m < 2; ++m) {
        const float* qp = qh + (qrow0 + m * 16 + l15) * D_ + h * DH_ + kt * 32 + lg * 8;
#pragma unroll
        for (int j = 0; j < 8; ++j) afr[m][j] = (__bf16)qp[j];
      }
#pragma unroll
      for (int n = 0; n < 4; ++n) {
        const float* kp = kh + ((size_t)(b * S_) + w * 64 + n * 16 + l15) * D_
                          + h * DH_ + kt * 32 + lg * 8;
        bf16x8 bfr;
#pragma unroll
        for (int j = 0; j < 8; ++j) bfr[j] = (__bf16)kp[j];
#pragma unroll
        for (int m = 0; m < 2; ++m)
          qk[m][n] = __builtin_amdgcn_mfma_f32_16x16x32_bf16(afr[m], bfr, qk[m][n], 0, 0, 0);
      }
    }
    // ---- scale + mask ----
#pragma unroll
    for (int m = 0; m < 2; ++m)
#pragma unroll
      for (int n = 0; n < 4; ++n)
#pragma unroll
        for (int i = 0; i < 4; ++i)
          qk[m][n][i] = qk[m][n][i] * 0.125f + madd[n];
    // ---- row max: in-lane over n, shfl over 16-lane col group, LDS x-wave ---
    float pm[2][4];
#pragma unroll
    for (int m = 0; m < 2; ++m)
#pragma unroll
      for (int i = 0; i < 4; ++i) {
        float v = fmaxf(fmaxf(qk[m][0][i], qk[m][1][i]), fmaxf(qk[m][2][i], qk[m][3][i]));
        pm[m][i] = rmax16(v);
      }
    if (l15 == 0) {
#pragma unroll
      for (int m = 0; m < 2; ++m)
#pragma unroll
        for (int i = 0; i < 4; ++i) maxred[w][m * 16 + lg * 4 + i] = pm[m][i];
    }
    __syncthreads();
    float gm[2][4], ps[2][4];
#pragma unroll
    for (int m = 0; m < 2; ++m)
#pragma unroll
      for (int i = 0; i < 4; ++i) {
        int row = m * 16 + lg * 4 + i;
        gm[m][i] = fmaxf(fmaxf(maxred[0][row], maxred[1][row]),
                         fmaxf(maxred[2][row], maxred[3][row]));
        ps[m][i] = 0.f;
      }
    // ---- exp + row sum ----
#pragma unroll
    for (int m = 0; m < 2; ++m)
#pragma unroll
      for (int n = 0; n < 4; ++n)
#pragma unroll
        for (int i = 0; i < 4; ++i) {
          float e = __expf(qk[m][n][i] - gm[m][i]);
          qk[m][n][i] = e;
          ps[m][i] += e;
        }
#pragma unroll
    for (int m = 0; m < 2; ++m)
#pragma unroll
      for (int i = 0; i < 4; ++i) pm[m][i] = rsum16(ps[m][i]);
    if (l15 == 0) {
#pragma unroll
      for (int m = 0; m < 2; ++m)
#pragma unroll
        for (int i = 0; i < 4; ++i) sumred[w][m * 16 + lg * 4 + i] = pm[m][i];
    }
    __syncthreads();
    // ---- normalize, accumulate av, write P (bf16) to LDS ----
#pragma unroll
    for (int m = 0; m < 2; ++m)
#pragma unroll
      for (int i = 0; i < 4; ++i) {
        int row = m * 16 + lg * 4 + i;
        float inv = 1.f / (sumred[0][row] + sumred[1][row] + sumred[2][row] + sumred[3][row]);
#pragma unroll
        for (int n = 0; n < 4; ++n) {
          float p = qk[m][n][i] * inv;
          av[m][n][i] += p * 0.125f;
          p_lds[row][w * 64 + n * 16 + l15] = (__bf16)p;
        }
      }
    __syncthreads();
    // ---- PV: A from p_lds (b128), B from v_lds (u16 gather), 16 MFMA -------
    f32x4 pv[2];
    pv[0] = (f32x4){0.f, 0.f, 0.f, 0.f};
    pv[1] = (f32x4){0.f, 0.f, 0.f, 0.f};
#pragma unroll
    for (int ks = 0; ks < 8; ++ks) {
      bf16x8 vb;
#pragma unroll
      for (int j = 0; j < 8; ++j) vb[j] = v_lds[ks * 32 + lg * 8 + j][w * 16 + l15];
#pragma unroll
      for (int m = 0; m < 2; ++m) {
        bf16x8 pa = *(const bf16x8*)&p_lds[m * 16 + l15][ks * 32 + lg * 8];
        pv[m] = __builtin_amdgcn_mfma_f32_16x16x32_bf16(pa, vb, pv[m], 0, 0, 0);
      }
    }
#pragma unroll
    for (int m = 0; m < 2; ++m)
#pragma unroll
      for (int i = 0; i < 4; ++i)
        ctx[(qrow0 + m * 16 + lg * 4 + i) * D_ + h * DH_ + w * 16 + l15] = pv[m][i];
  }
  // ---- head-averaged weights, written once (no atomics) ----
#pragma unroll
  for (int m = 0; m < 2; ++m)
#pragma unroll
    for (int i = 0; i < 4; ++i) {
      size_t arow = (qrow0 + m * 16 + lg * 4 + i) * S_;
#pragma unroll
      for (int n = 0; n < 4; ++n)
        avout[arow + w * 64 + n * 16 + l15] = av[m][n][i];
    }
}

// ---------------- x1 = LN(a + r) --------------------------------------------
__global__ __launch_bounds__(256) void ln_add_k(const float* __restrict__ a,
    const float* __restrict__ r, const float* __restrict__ g,
    const float* __restrict__ be, float* __restrict__ out) {
  size_t row = (size_t)blockIdx.x * D_;
  int tid = threadIdx.x;
  __shared__ float red[256];
  float v0 = a[row + tid]       + r[row + tid];
  float v1 = a[row + tid + 256] + r[row + tid + 256];
  red[tid] = v0 + v1;
  __syncthreads();
  for (int o = 128; o > 0; o >>= 1) { if (tid < o) red[tid] += red[tid + o]; __syncthreads(); }
  float mean = red[0] * (1.f / D_);
  __syncthreads();
  red[tid] = v0 * v0 + v1 * v1;
  __syncthreads();
  for (int o = 128; o > 0; o >>= 1) { if (tid < o) red[tid] += red[tid + o]; __syncthreads(); }
  float var = red[0] * (1.f / D_) - mean * mean;
  float rstd = rsqrtf(var + 1e-5f);
  out[row + tid]       = (v0 - mean) * rstd * g[tid]       + be[tid];
  out[row + tid + 256] = (v1 - mean) * rstd * g[tid + 256] + be[tid + 256];
}

// ---------------- out[i] = LN(leaky(h1)+x1) gathered to ragged rows ----------
__global__ __launch_bounds__(256) void final_k(const float* __restrict__ h1,
    const float* __restrict__ x1, const int* __restrict__ gb,
    const int* __restrict__ starts, const float* __restrict__ g,
    const float* __restrict__ be, float* __restrict__ out, int Lmax) {
  int i = blockIdx.x, tid = threadIdx.x;
  int b = gb[i], p = i - starts[b];
  size_t row = ((size_t)b * Lmax + p) * D_;
  __shared__ float red[256];
  float t0 = h1[row + tid];       t0 = (t0 >= 0.f) ? t0 : 0.01f * t0; t0 += x1[row + tid];
  float t1 = h1[row + tid + 256]; t1 = (t1 >= 0.f) ? t1 : 0.01f * t1; t1 += x1[row + tid + 256];
  red[tid] = t0 + t1;
  __syncthreads();
  for (int o = 128; o > 0; o >>= 1) { if (tid < o) red[tid] += red[tid + o]; __syncthreads(); }
  float mean = red[0] * (1.f / D_);
  __syncthreads();
  red[tid] = t0 * t0 + t1 * t1;
  __syncthreads();
  for (int o = 128; o > 0; o >>= 1) { if (tid < o) red[tid] += red[tid + o]; __syncthreads(); }
  float var = red[0] * (1.f / D_) - mean * mean;
  float rstd = rsqrtf(var + 1e-5f);
  out[(size_t)i * D_ + tid]       = (t0 - mean) * rstd * g[tid]       + be[tid];
  out[(size_t)i * D_ + tid + 256] = (t1 - mean) * rstd * g[tid + 256] + be[tid + 256];
}

// ---------------- host launcher ----------------------------------------------
extern "C" void kernel_launch(void* const* d_in, const int* in_sizes, int n_in,
                              void* d_out, int out_size, void* d_ws, size_t ws_size,
                              hipStream_t stream) {
  const float* nodes = (const float*)d_in[0];
  const int*   gb    = (const int*)d_in[1];
  const float* cond  = (const float*)d_in[2];
  const void*  maskp = d_in[3];
  const float* Wq   = (const float*)d_in[6];
  const float* bq   = (const float*)d_in[7];
  const float* Wk   = (const float*)d_in[8];
  const float* bk   = (const float*)d_in[9];
  const float* Wv   = (const float*)d_in[10];
  const float* bv   = (const float*)d_in[11];
  const float* in_w = (const float*)d_in[12];
  const float* in_b = (const float*)d_in[13];
  const float* Wo   = (const float*)d_in[14];
  const float* bo   = (const float*)d_in[15];
  const float* g1   = (const float*)d_in[16];
  const float* b1ln = (const float*)d_in[17];
  const float* W1   = (const float*)d_in[18];
  const float* b1f  = (const float*)d_in[19];
  const float* g2   = (const float*)d_in[20];
  const float* b2ln = (const float*)d_in[21];

  const int N    = in_sizes[0] / D_;                    // 12032
  const int Lmax = (out_size - N * D_) / (B_ * S_);     // 992
  const int BL   = B_ * Lmax;                           // 15872

  float* ws = (float*)d_ws;
  int* starts = (int*)(ws + 0);
  int* maskc  = (int*)(ws + 64);
  size_t o = 8192;
  float* dense = ws + o; o += (size_t)BL * D_;
  float* qh    = ws + o; o += (size_t)BL * D_;
  float* ctx   = qh;              // alias safe: head-h Q read before head-h ctx write, same rows
  float* kh    = ws + o; o += (size_t)B_ * S_ * D_;
  float* vh    = ws + o; o += (size_t)B_ * S_ * D_;
  float* tmp   = ws + o; o += (size_t)BL * D_;
  float* x1    = ws + o; o += (size_t)BL * D_;
  float* h1    = dense;           // alias: dense dead after ln_add_k
  float* Wqp = ws + o; o += (size_t)D_ * D_;
  float* Wkp = ws + o; o += (size_t)LAT_ * D_;
  float* Wvp = ws + o; o += (size_t)LAT_ * D_;
  float* bqp = ws + o; o += D_;
  float* bkp = ws + o; o += D_;
  float* bvp = ws + o; o += D_;
  unsigned short* iw0_pk = (unsigned short*)(ws + o); o += (size_t)D_ * D_ / 2;
  unsigned short* iw1_pk = (unsigned short*)(ws + o); o += (size_t)D_ * D_ / 2;
  unsigned short* iw2_pk = (unsigned short*)(ws + o); o += (size_t)D_ * D_ / 2;
  unsigned short* Wqp_pk = (unsigned short*)(ws + o); o += (size_t)D_ * D_ / 2;
  unsigned short* Wkp_pk = (unsigned short*)(ws + o); o += (size_t)LAT_ * D_ / 2;
  unsigned short* Wvp_pk = (unsigned short*)(ws + o); o += (size_t)LAT_ * D_ / 2;
  unsigned short* Wo_pk  = (unsigned short*)(ws + o); o += (size_t)D_ * D_ / 2;
  unsigned short* W1_pk  = (unsigned short*)(ws + o); o += (size_t)D_ * D_ / 2;

  (void)hipMemsetAsync(d_ws, 0, (8192 + (size_t)BL * D_) * sizeof(float), stream);

  mask_canon_k<<<(B_ * S_ + 255) / 256, 256, 0, stream>>>(maskp, maskc, B_ * S_);
  starts_k<<<(N + 255) / 256, 256, 0, stream>>>(gb, starts, N);
  scatter_k<<<N, 256, 0, stream>>>(nodes, gb, starts, dense, Lmax);

  pack_b_k<<<(D_ / 8) * 512 / 256, 256, 0, stream>>>(in_w,               iw0_pk, D_);
  pack_b_k<<<(D_ / 8) * 512 / 256, 256, 0, stream>>>(in_w + D_ * D_,     iw1_pk, D_);
  pack_b_k<<<(D_ / 8) * 512 / 256, 256, 0, stream>>>(in_w + 2 * D_ * D_, iw2_pk, D_);
  pack_b_k<<<(D_ / 8) * 512 / 256, 256, 0, stream>>>(Wo, Wo_pk, D_);
  pack_b_k<<<(D_ / 8) * 512 / 256, 256, 0, stream>>>(W1, W1_pk, D_);

  mgemm_k<<<dim3(4, D_ / 128), 256, 0, stream>>>(Wq, iw0_pk, nullptr, Wqp, D_, D_, D_);
  mgemm_k<<<dim3(4, LAT_ / 128), 256, 0, stream>>>(Wk, iw1_pk, nullptr, Wkp, LAT_, D_, D_);
  mgemm_k<<<dim3(4, LAT_ / 128), 256, 0, stream>>>(Wv, iw2_pk, nullptr, Wvp, LAT_, D_, D_);
  pack_b_k<<<(D_ / 8) * 512 / 256, 256, 0, stream>>>(Wqp, Wqp_pk, D_);
  pack_b_k<<<(LAT_ / 8) * 512 / 256, 256, 0, stream>>>(Wkp, Wkp_pk, LAT_);
  pack_b_k<<<(LAT_ / 8) * 512 / 256, 256, 0, stream>>>(Wvp, Wvp_pk, LAT_);
  bias_comb_k<<<2, 256, 0, stream>>>(bq, in_w,               in_b,          bqp);
  bias_comb_k<<<2, 256, 0, stream>>>(bk, in_w + D_ * D_,     in_b + D_,     bkp);
  bias_comb_k<<<2, 256, 0, stream>>>(bv, in_w + 2 * D_ * D_, in_b + 2 * D_, bvp);

  mgemm_k<<<dim3(4, BL / 128), 256, 0, stream>>>(dense, Wqp_pk, bqp, qh, BL, D_, D_);
  mgemm_k<<<dim3(4, (B_ * S_) / 128), 256, 0, stream>>>(cond, Wkp_pk, bkp, kh, B_ * S_, D_, LAT_);
  mgemm_k<<<dim3(4, (B_ * S_) / 128), 256, 0, stream>>>(cond, Wvp_pk, bvp, vh, B_ * S_, D_, LAT_);

  attn_k<<<(Lmax / 32) * B_, 256, 0, stream>>>(qh, kh, vh, maskc, ctx,
      (float*)d_out + (size_t)N * D_, Lmax);

  mgemm_k<<<dim3(4, BL / 128), 256, 0, stream>>>(ctx, Wo_pk, bo, tmp, BL, D_, D_);
  ln_add_k<<<BL, 256, 0, stream>>>(tmp, dense, g1, b1ln, x1);

  mgemm_k<<<dim3(4, BL / 128), 256, 0, stream>>>(x1, W1_pk, b1f, h1, BL, D_, D_);
  final_k<<<N, 256, 0, stream>>>(h1, x1, gb, starts, g2, b2ln, (float*)d_out, Lmax);
}

// Round 7
// 267.031 us; speedup vs baseline: 4.4951x; 1.4409x over previous
//
#include <hip/hip_runtime.h>
#include <math.h>

#define D_   512
#define LAT_ 768
#define B_   16
#define S_   256
#define H_   8
#define DH_  64

typedef __bf16 bf16x8 __attribute__((ext_vector_type(8)));
typedef float f32x4 __attribute__((ext_vector_type(4)));

__device__ __forceinline__ unsigned short f2bf(float f) {
  unsigned u = __float_as_uint(f);
  unsigned r = (u + 0x7fffu + ((u >> 16) & 1u)) >> 16;
  return (unsigned short)r;
}

// ---------------- mask canonicalization (detect u8 / i32 / f32 storage) ------
__global__ void mask_canon_k(const void* __restrict__ mask, int* __restrict__ out, int n) {
  int i = blockIdx.x * blockDim.x + threadIdx.x;
  if (i >= n) return;
  const unsigned char* pb = (const unsigned char*)mask;
  const int*   pi = (const int*)mask;
  const float* pf = (const float*)mask;
  unsigned int w = ((const unsigned int*)mask)[1023];
  int v;
  if (w == 0x01010101u)      v = pb[i];
  else if (w == 0x3f800000u) v = (pf[i] != 0.0f);
  else                       v = (pi[i] != 0);
  out[i] = v ? 1 : 0;
}

// ---------------- segment starts (graph_batch is sorted) ---------------------
__global__ void starts_k(const int* __restrict__ gb, int* __restrict__ starts, int n) {
  int i = blockIdx.x * blockDim.x + threadIdx.x;
  if (i >= n) return;
  if (i == 0 || gb[i] != gb[i - 1]) starts[gb[i]] = i;
}

// ---------------- scatter ragged nodes -> dense [B,Lmax,D] -------------------
__global__ __launch_bounds__(256) void scatter_k(const float* __restrict__ nodes,
    const int* __restrict__ gb, const int* __restrict__ starts,
    float* __restrict__ dense, int Lmax) {
  int i = blockIdx.x;
  int b = gb[i], p = i - starts[b];
  const float* src = nodes + (size_t)i * D_;
  float* dst = dense + ((size_t)b * Lmax + p) * D_;
  dst[threadIdx.x]       = src[threadIdx.x];
  dst[threadIdx.x + 256] = src[threadIdx.x + 256];
}

// ---------------- pack one (kc,n) chunk of B into MFMA layout ----------------
// out idx = ((nt+ntoff)*KT + kt)*4096 + nblk*512 + kblk*128 + col*8 + j
__device__ __forceinline__ void pack_chunk(const float* __restrict__ W,
    unsigned short* __restrict__ out, int K, int ntoff, int idx) {
  int n = idx & 511, kc = idx >> 9;
  int kt = kc >> 2, kblk = kc & 3;
  int nt = n >> 7, nblk = (n >> 4) & 7, col = n & 15;
  int KT = K >> 5;
  size_t ob = ((size_t)((nt + ntoff) * KT + kt) * 4096) + nblk * 512 + kblk * 128 + col * 8;
  unsigned short v[8];
#pragma unroll
  for (int j = 0; j < 8; ++j) v[j] = f2bf(W[(size_t)(kc * 8 + j) * 512 + n]);
  int4 pk;
  pk.x = v[0] | (v[1] << 16); pk.y = v[2] | (v[3] << 16);
  pk.z = v[4] | (v[5] << 16); pk.w = v[6] | (v[7] << 16);
  *(int4*)&out[ob] = pk;
}

// stage-1 packs: in_w0/1/2, Wo, W1 (all [512][512]) — one dispatch, 640 blocks
__global__ __launch_bounds__(256) void pack1_k(const float* __restrict__ in_w,
    const float* __restrict__ Wo, const float* __restrict__ W1,
    unsigned short* iw0, unsigned short* iw1, unsigned short* iw2,
    unsigned short* Wo_pk, unsigned short* W1_pk) {
  int bid = blockIdx.x, sel = bid >> 7, within = bid & 127;
  const float* W; unsigned short* out;
  switch (sel) {
    case 0: W = in_w;               out = iw0;   break;
    case 1: W = in_w + 512 * 512;   out = iw1;   break;
    case 2: W = in_w + 2 * 512 * 512; out = iw2; break;
    case 3: W = Wo;                 out = Wo_pk; break;
    default: W = W1;                out = W1_pk; break;
  }
  pack_chunk(W, out, 512, 0, within * 256 + threadIdx.x);
}

// stage-2 packs: Wqp (K=512) -> Wqp_pk; Wkp/Wvp (K=768) -> kv_pk (ntoff 0 / 4)
__global__ __launch_bounds__(256) void pack2_k(const float* __restrict__ Wqp,
    const float* __restrict__ Wkp, const float* __restrict__ Wvp,
    unsigned short* Wqp_pk, unsigned short* kv_pk) {
  int bid = blockIdx.x, tid = threadIdx.x;
  if (bid < 128)      pack_chunk(Wqp, Wqp_pk, 512, 0, bid * 256 + tid);
  else if (bid < 320) pack_chunk(Wkp, kv_pk, 768, 0, (bid - 128) * 256 + tid);
  else                pack_chunk(Wvp, kv_pk, 768, 4, (bid - 320) * 256 + tid);
}

// ---------------- 64x128-tile bf16 MFMA GEMM body ----------------------------
// 4 waves (2x2 of 32x64); 8x mfma_16x16x32_bf16 per K-step.
__device__ __forceinline__ void mgemm64(const float* __restrict__ A,
    const unsigned short* __restrict__ Bpk, const float* __restrict__ bias,
    float* __restrict__ C, int M, int N, int K, int xt, int yt,
    unsigned short* Al, unsigned short* Bl) {
  const int tid = threadIdx.x;
  const int lane = tid & 63, wid = tid >> 6;
  const int wr = wid >> 1, wc = wid & 1;
  const int row0 = yt * 64, col0 = xt * 128;
  const int KT = K >> 5;
  f32x4 acc[2][4];
#pragma unroll
  for (int m = 0; m < 2; ++m)
#pragma unroll
    for (int n = 0; n < 4; ++n) acc[m][n] = (f32x4){0.f, 0.f, 0.f, 0.f};
  const int kb0 = tid & 3, ar = tid >> 2;
  const unsigned short* bsrc = Bpk + (size_t)xt * KT * 4096;

  for (int kt = 0; kt < KT; ++kt) {
    {
      const unsigned short* g1 = bsrc + (size_t)kt * 4096 + wid * 512 + lane * 8;
      __builtin_amdgcn_global_load_lds(
          (const __attribute__((address_space(1))) void*)g1,
          (__attribute__((address_space(3))) void*)&Bl[wid * 512], 16, 0, 0);
      __builtin_amdgcn_global_load_lds(
          (const __attribute__((address_space(1))) void*)(g1 + 2048),
          (__attribute__((address_space(3))) void*)&Bl[2048 + wid * 512], 16, 0, 0);
    }
    {
      const float* ap = A + (size_t)(row0 + ar) * K + kt * 32 + kb0 * 8;
      float4 f0 = *(const float4*)ap;
      float4 f1 = *(const float4*)(ap + 4);
      int4 pk;
      pk.x = f2bf(f0.x) | (f2bf(f0.y) << 16);
      pk.y = f2bf(f0.z) | (f2bf(f0.w) << 16);
      pk.z = f2bf(f1.x) | (f2bf(f1.y) << 16);
      pk.w = f2bf(f1.z) | (f2bf(f1.w) << 16);
      *(int4*)&Al[(ar >> 4) * 512 + kb0 * 128 + (ar & 15) * 8] = pk;
    }
    __syncthreads();
    bf16x8 af[2], bfr[4];
#pragma unroll
    for (int m = 0; m < 2; ++m)
      af[m] = *(const bf16x8*)&Al[(wr * 2 + m) * 512 + lane * 8];
#pragma unroll
    for (int n = 0; n < 4; ++n)
      bfr[n] = *(const bf16x8*)&Bl[(wc * 4 + n) * 512 + lane * 8];
#pragma unroll
    for (int m = 0; m < 2; ++m)
#pragma unroll
      for (int n = 0; n < 4; ++n)
        acc[m][n] = __builtin_amdgcn_mfma_f32_16x16x32_bf16(af[m], bfr[n], acc[m][n], 0, 0, 0);
    __syncthreads();
  }
  const int cl = lane & 15, rg = lane >> 4;
  float bv[4];
#pragma unroll
  for (int n = 0; n < 4; ++n)
    bv[n] = bias ? bias[col0 + wc * 64 + n * 16 + cl] : 0.f;
#pragma unroll
  for (int m = 0; m < 2; ++m) {
    int r = row0 + wr * 32 + m * 16 + rg * 4;
#pragma unroll
    for (int n = 0; n < 4; ++n) {
      int c = col0 + wc * 64 + n * 16 + cl;
#pragma unroll
      for (int i = 0; i < 4; ++i)
        C[(size_t)(r + i) * N + c] = acc[m][n][i] + bv[n];
    }
  }
}

// plain grid GEMM (Wo, W1): grid (N/128, M/64)
__global__ __launch_bounds__(256) void gemm64_k(const float* __restrict__ A,
    const unsigned short* __restrict__ Bpk, const float* __restrict__ bias,
    float* __restrict__ C, int M, int N, int K) {
  __shared__ __align__(16) unsigned short Al[2048];
  __shared__ __align__(16) unsigned short Bl[4096];
  mgemm64(A, Bpk, bias, C, M, N, K, blockIdx.x, blockIdx.y, Al, Bl);
}

// fused weight-fold GEMMs (3 of them), 128 blocks total
__global__ __launch_bounds__(256) void fold_k(const float* __restrict__ Wq,
    const float* __restrict__ Wk, const float* __restrict__ Wv,
    const unsigned short* iw0, const unsigned short* iw1, const unsigned short* iw2,
    float* Wqp, float* Wkp, float* Wvp) {
  __shared__ __align__(16) unsigned short Al[2048];
  __shared__ __align__(16) unsigned short Bl[4096];
  int bid = blockIdx.x;
  if (bid < 32)       mgemm64(Wq, iw0, nullptr, Wqp, 512, 512, 512, bid & 3, bid >> 2, Al, Bl);
  else if (bid < 80)  { int r = bid - 32; mgemm64(Wk, iw1, nullptr, Wkp, 768, 512, 512, r & 3, r >> 2, Al, Bl); }
  else                { int r = bid - 80; mgemm64(Wv, iw2, nullptr, Wvp, 768, 512, 512, r & 3, r >> 2, Al, Bl); }
}

// fused qh + kv projection GEMMs: 992 + 512 = 1504 blocks
__global__ __launch_bounds__(256) void proj_k(const float* __restrict__ dense,
    const float* __restrict__ cond, const unsigned short* Wqp_pk,
    const unsigned short* kv_pk, const float* __restrict__ bqp,
    const float* __restrict__ bkv, float* qh, float* kvh, int BL) {
  __shared__ __align__(16) unsigned short Al[2048];
  __shared__ __align__(16) unsigned short Bl[4096];
  int bid = blockIdx.x;
  int nq = (BL >> 6) << 2;   // 992
  if (bid < nq)
    mgemm64(dense, Wqp_pk, bqp, qh, BL, 512, 512, bid & 3, bid >> 2, Al, Bl);
  else {
    int r = bid - nq;
    mgemm64(cond, kv_pk, bkv, kvh, B_ * S_, 1024, LAT_, r & 7, r >> 3, Al, Bl);
  }
}

// fold biases: out = bin @ in_w_x + in_b_x  (6 blocks)
__global__ void bias3_k(const float* __restrict__ bq, const float* __restrict__ bk,
    const float* __restrict__ bv, const float* __restrict__ in_w,
    const float* __restrict__ in_b, float* bqp, float* bkv) {
  int sel = blockIdx.x >> 1;
  int j = (blockIdx.x & 1) * 256 + threadIdx.x;
  const float* bin; const float* W; const float* badd; float* out;
  if (sel == 0)      { bin = bq; W = in_w;                 badd = in_b;          out = bqp; }
  else if (sel == 1) { bin = bk; W = in_w + 512 * 512;     badd = in_b + D_;     out = bkv; }
  else               { bin = bv; W = in_w + 2 * 512 * 512; badd = in_b + 2 * D_; out = bkv + 512; }
  float s = badd[j];
  for (int k = 0; k < D_; ++k) s += bin[k] * W[(size_t)k * D_ + j];
  out[j] = s;
}

// ---------------- MFMA attention (kvh row stride 1024; vh = kvh+512) ---------
__device__ __forceinline__ float rmax16(float v) {
  v = fmaxf(v, __shfl_xor(v, 1)); v = fmaxf(v, __shfl_xor(v, 2));
  v = fmaxf(v, __shfl_xor(v, 4)); v = fmaxf(v, __shfl_xor(v, 8));
  return v;
}
__device__ __forceinline__ float rsum16(float v) {
  v += __shfl_xor(v, 1); v += __shfl_xor(v, 2);
  v += __shfl_xor(v, 4); v += __shfl_xor(v, 8);
  return v;
}

__global__ __launch_bounds__(256) void attn_k(const float* __restrict__ qh,
    const float* __restrict__ kvh, const int* __restrict__ maskc,
    float* __restrict__ ctx, float* __restrict__ avout, int Lmax) {
  const int bid = blockIdx.x;
  const int b = bid & 15;
  const int l0 = (bid >> 4) * 32;
  const int tid = threadIdx.x;
  const int lane = tid & 63, w = tid >> 6;
  const int lg = lane >> 4, l15 = lane & 15;
  __shared__ __align__(16) __bf16 v_lds[256][72];
  __shared__ __align__(16) __bf16 p_lds[32][264];
  __shared__ float maxred[4][32];
  __shared__ float sumred[4][32];
  __shared__ float mask_s[S_];
  mask_s[tid] = maskc[b * S_ + tid] ? -1.0e30f : 0.f;
  __syncthreads();
  float madd[4];
#pragma unroll
  for (int n = 0; n < 4; ++n) madd[n] = mask_s[w * 64 + n * 16 + l15];

  float av[2][4][4];
#pragma unroll
  for (int m = 0; m < 2; ++m)
#pragma unroll
    for (int n = 0; n < 4; ++n)
#pragma unroll
      for (int i = 0; i < 4; ++i) av[m][n][i] = 0.f;

  const size_t qrow0 = (size_t)b * Lmax + l0;
  const int srow = tid >> 2, scol = (tid & 3) * 16;

#pragma unroll 1
  for (int h = 0; h < H_; ++h) {
    __syncthreads();
#pragma unroll
    for (int pass = 0; pass < 4; ++pass) {
      int s = pass * 64 + srow;
      const float* vp = kvh + (size_t)(b * S_ + s) * 1024 + 512 + h * DH_ + scol;
      bf16x8 t0, t1;
#pragma unroll
      for (int j = 0; j < 8; ++j) { t0[j] = (__bf16)vp[j]; t1[j] = (__bf16)vp[8 + j]; }
      *(bf16x8*)&v_lds[s][scol]     = t0;
      *(bf16x8*)&v_lds[s][scol + 8] = t1;
    }
    f32x4 qk[2][4];
#pragma unroll
    for (int m = 0; m < 2; ++m)
#pragma unroll
      for (int n = 0; n < 4; ++n) qk[m][n] = (f32x4){0.f, 0.f, 0.f, 0.f};
#pragma unroll
    for (int kt = 0; kt < 2; ++kt) {
      bf16x8 afr[2];
#pragma unroll
      for (int m = 0; m < 2; ++m) {
        const float* qp = qh + (qrow0 + m * 16 + l15) * D_ + h * DH_ + kt * 32 + lg * 8;
#pragma unroll
        for (int j = 0; j < 8; ++j) afr[m][j] = (__bf16)qp[j];
      }
#pragma unroll
      for (int n = 0; n < 4; ++n) {
        const float* kp = kvh + ((size_t)(b * S_) + w * 64 + n * 16 + l15) * 1024
                          + h * DH_ + kt * 32 + lg * 8;
        bf16x8 bfr;
#pragma unroll
        for (int j = 0; j < 8; ++j) bfr[j] = (__bf16)kp[j];
#pragma unroll
        for (int m = 0; m < 2; ++m)
          qk[m][n] = __builtin_amdgcn_mfma_f32_16x16x32_bf16(afr[m], bfr, qk[m][n], 0, 0, 0);
      }
    }
#pragma unroll
    for (int m = 0; m < 2; ++m)
#pragma unroll
      for (int n = 0; n < 4; ++n)
#pragma unroll
        for (int i = 0; i < 4; ++i)
          qk[m][n][i] = qk[m][n][i] * 0.125f + madd[n];
    float pm[2][4];
#pragma unroll
    for (int m = 0; m < 2; ++m)
#pragma unroll
      for (int i = 0; i < 4; ++i) {
        float v = fmaxf(fmaxf(qk[m][0][i], qk[m][1][i]), fmaxf(qk[m][2][i], qk[m][3][i]));
        pm[m][i] = rmax16(v);
      }
    if (l15 == 0) {
#pragma unroll
      for (int m = 0; m < 2; ++m)
#pragma unroll
        for (int i = 0; i < 4; ++i) maxred[w][m * 16 + lg * 4 + i] = pm[m][i];
    }
    __syncthreads();
    float gm[2][4], ps[2][4];
#pragma unroll
    for (int m = 0; m < 2; ++m)
#pragma unroll
      for (int i = 0; i < 4; ++i) {
        int row = m * 16 + lg * 4 + i;
        gm[m][i] = fmaxf(fmaxf(maxred[0][row], maxred[1][row]),
                         fmaxf(maxred[2][row], maxred[3][row]));
        ps[m][i] = 0.f;
      }
#pragma unroll
    for (int m = 0; m < 2; ++m)
#pragma unroll
      for (int n = 0; n < 4; ++n)
#pragma unroll
        for (int i = 0; i < 4; ++i) {
          float e = __expf(qk[m][n][i] - gm[m][i]);
          qk[m][n][i] = e;
          ps[m][i] += e;
        }
#pragma unroll
    for (int m = 0; m < 2; ++m)
#pragma unroll
      for (int i = 0; i < 4; ++i) pm[m][i] = rsum16(ps[m][i]);
    if (l15 == 0) {
#pragma unroll
      for (int m = 0; m < 2; ++m)
#pragma unroll
        for (int i = 0; i < 4; ++i) sumred[w][m * 16 + lg * 4 + i] = pm[m][i];
    }
    __syncthreads();
#pragma unroll
    for (int m = 0; m < 2; ++m)
#pragma unroll
      for (int i = 0; i < 4; ++i) {
        int row = m * 16 + lg * 4 + i;
        float inv = 1.f / (sumred[0][row] + sumred[1][row] + sumred[2][row] + sumred[3][row]);
#pragma unroll
        for (int n = 0; n < 4; ++n) {
          float p = qk[m][n][i] * inv;
          av[m][n][i] += p * 0.125f;
          p_lds[row][w * 64 + n * 16 + l15] = (__bf16)p;
        }
      }
    __syncthreads();
    f32x4 pv[2];
    pv[0] = (f32x4){0.f, 0.f, 0.f, 0.f};
    pv[1] = (f32x4){0.f, 0.f, 0.f, 0.f};
#pragma unroll
    for (int ks = 0; ks < 8; ++ks) {
      bf16x8 vb;
#pragma unroll
      for (int j = 0; j < 8; ++j) vb[j] = v_lds[ks * 32 + lg * 8 + j][w * 16 + l15];
#pragma unroll
      for (int m = 0; m < 2; ++m) {
        bf16x8 pa = *(const bf16x8*)&p_lds[m * 16 + l15][ks * 32 + lg * 8];
        pv[m] = __builtin_amdgcn_mfma_f32_16x16x32_bf16(pa, vb, pv[m], 0, 0, 0);
      }
    }
#pragma unroll
    for (int m = 0; m < 2; ++m)
#pragma unroll
      for (int i = 0; i < 4; ++i)
        ctx[(qrow0 + m * 16 + lg * 4 + i) * D_ + h * DH_ + w * 16 + l15] = pv[m][i];
  }
#pragma unroll
  for (int m = 0; m < 2; ++m)
#pragma unroll
    for (int i = 0; i < 4; ++i) {
      size_t arow = (qrow0 + m * 16 + lg * 4 + i) * S_;
#pragma unroll
      for (int n = 0; n < 4; ++n)
        avout[arow + w * 64 + n * 16 + l15] = av[m][n][i];
    }
}

// ---------------- x1 = LN(a + r) --------------------------------------------
__global__ __launch_bounds__(256) void ln_add_k(const float* __restrict__ a,
    const float* __restrict__ r, const float* __restrict__ g,
    const float* __restrict__ be, float* __restrict__ out) {
  size_t row = (size_t)blockIdx.x * D_;
  int tid = threadIdx.x;
  __shared__ float red[256];
  float v0 = a[row + tid]       + r[row + tid];
  float v1 = a[row + tid + 256] + r[row + tid + 256];
  red[tid] = v0 + v1;
  __syncthreads();
  for (int o = 128; o > 0; o >>= 1) { if (tid < o) red[tid] += red[tid + o]; __syncthreads(); }
  float mean = red[0] * (1.f / D_);
  __syncthreads();
  red[tid] = v0 * v0 + v1 * v1;
  __syncthreads();
  for (int o = 128; o > 0; o >>= 1) { if (tid < o) red[tid] += red[tid + o]; __syncthreads(); }
  float var = red[0] * (1.f / D_) - mean * mean;
  float rstd = rsqrtf(var + 1e-5f);
  out[row + tid]       = (v0 - mean) * rstd * g[tid]       + be[tid];
  out[row + tid + 256] = (v1 - mean) * rstd * g[tid + 256] + be[tid + 256];
}

// ---------------- out[i] = LN(leaky(h1)+x1) gathered to ragged rows ----------
__global__ __launch_bounds__(256) void final_k(const float* __restrict__ h1,
    const float* __restrict__ x1, const int* __restrict__ gb,
    const int* __restrict__ starts, const float* __restrict__ g,
    const float* __restrict__ be, float* __restrict__ out, int Lmax) {
  int i = blockIdx.x, tid = threadIdx.x;
  int b = gb[i], p = i - starts[b];
  size_t row = ((size_t)b * Lmax + p) * D_;
  __shared__ float red[256];
  float t0 = h1[row + tid];       t0 = (t0 >= 0.f) ? t0 : 0.01f * t0; t0 += x1[row + tid];
  float t1 = h1[row + tid + 256]; t1 = (t1 >= 0.f) ? t1 : 0.01f * t1; t1 += x1[row + tid + 256];
  red[tid] = t0 + t1;
  __syncthreads();
  for (int o = 128; o > 0; o >>= 1) { if (tid < o) red[tid] += red[tid + o]; __syncthreads(); }
  float mean = red[0] * (1.f / D_);
  __syncthreads();
  red[tid] = t0 * t0 + t1 * t1;
  __syncthreads();
  for (int o = 128; o > 0; o >>= 1) { if (tid < o) red[tid] += red[tid + o]; __syncthreads(); }
  float var = red[0] * (1.f / D_) - mean * mean;
  float rstd = rsqrtf(var + 1e-5f);
  out[(size_t)i * D_ + tid]       = (t0 - mean) * rstd * g[tid]       + be[tid];
  out[(size_t)i * D_ + tid + 256] = (t1 - mean) * rstd * g[tid + 256] + be[tid + 256];
}

// ---------------- host launcher ----------------------------------------------
extern "C" void kernel_launch(void* const* d_in, const int* in_sizes, int n_in,
                              void* d_out, int out_size, void* d_ws, size_t ws_size,
                              hipStream_t stream) {
  const float* nodes = (const float*)d_in[0];
  const int*   gb    = (const int*)d_in[1];
  const float* cond  = (const float*)d_in[2];
  const void*  maskp = d_in[3];
  const float* Wq   = (const float*)d_in[6];
  const float* bq   = (const float*)d_in[7];
  const float* Wk   = (const float*)d_in[8];
  const float* bk   = (const float*)d_in[9];
  const float* Wv   = (const float*)d_in[10];
  const float* bv   = (const float*)d_in[11];
  const float* in_w = (const float*)d_in[12];
  const float* in_b = (const float*)d_in[13];
  const float* Wo   = (const float*)d_in[14];
  const float* bo   = (const float*)d_in[15];
  const float* g1   = (const float*)d_in[16];
  const float* b1ln = (const float*)d_in[17];
  const float* W1   = (const float*)d_in[18];
  const float* b1f  = (const float*)d_in[19];
  const float* g2   = (const float*)d_in[20];
  const float* b2ln = (const float*)d_in[21];

  const int N    = in_sizes[0] / D_;                    // 12032
  const int Lmax = (out_size - N * D_) / (B_ * S_);     // 992
  const int BL   = B_ * Lmax;                           // 15872

  float* ws = (float*)d_ws;
  int* starts = (int*)(ws + 0);
  int* maskc  = (int*)(ws + 64);
  size_t o = 8192;
  float* dense = ws + o; o += (size_t)BL * D_;
  float* qh    = ws + o; o += (size_t)BL * D_;
  float* ctx   = qh;              // alias safe: head-h Q read before head-h ctx write, same rows
  float* kvh   = ws + o; o += (size_t)B_ * S_ * 1024;   // [4096][1024]: kh | vh
  float* tmp   = ws + o; o += (size_t)BL * D_;
  float* x1    = ws + o; o += (size_t)BL * D_;
  float* h1    = dense;           // alias: dense dead after ln_add_k
  float* Wqp = ws + o; o += (size_t)D_ * D_;
  float* Wkp = ws + o; o += (size_t)LAT_ * D_;
  float* Wvp = ws + o; o += (size_t)LAT_ * D_;
  float* bqp = ws + o; o += D_;
  float* bkv = ws + o; o += 1024;
  unsigned short* iw0_pk = (unsigned short*)(ws + o); o += (size_t)D_ * D_ / 2;
  unsigned short* iw1_pk = (unsigned short*)(ws + o); o += (size_t)D_ * D_ / 2;
  unsigned short* iw2_pk = (unsigned short*)(ws + o); o += (size_t)D_ * D_ / 2;
  unsigned short* Wqp_pk = (unsigned short*)(ws + o); o += (size_t)D_ * D_ / 2;
  unsigned short* kv_pk  = (unsigned short*)(ws + o); o += (size_t)LAT_ * 1024 / 2;
  unsigned short* Wo_pk  = (unsigned short*)(ws + o); o += (size_t)D_ * D_ / 2;
  unsigned short* W1_pk  = (unsigned short*)(ws + o); o += (size_t)D_ * D_ / 2;

  (void)hipMemsetAsync(d_ws, 0, (8192 + (size_t)BL * D_) * sizeof(float), stream);

  mask_canon_k<<<(B_ * S_ + 255) / 256, 256, 0, stream>>>(maskp, maskc, B_ * S_);
  starts_k<<<(N + 255) / 256, 256, 0, stream>>>(gb, starts, N);
  scatter_k<<<N, 256, 0, stream>>>(nodes, gb, starts, dense, Lmax);

  pack1_k<<<640, 256, 0, stream>>>(in_w, Wo, W1, iw0_pk, iw1_pk, iw2_pk, Wo_pk, W1_pk);
  fold_k<<<128, 256, 0, stream>>>(Wq, Wk, Wv, iw0_pk, iw1_pk, iw2_pk, Wqp, Wkp, Wvp);
  pack2_k<<<512, 256, 0, stream>>>(Wqp, Wkp, Wvp, Wqp_pk, kv_pk);
  bias3_k<<<6, 256, 0, stream>>>(bq, bk, bv, in_w, in_b, bqp, bkv);

  proj_k<<<(BL >> 6) * 4 + 512, 256, 0, stream>>>(dense, cond, Wqp_pk, kv_pk,
      bqp, bkv, qh, kvh, BL);

  attn_k<<<(Lmax / 32) * B_, 256, 0, stream>>>(qh, kvh, maskc, ctx,
      (float*)d_out + (size_t)N * D_, Lmax);

  gemm64_k<<<dim3(4, BL / 64), 256, 0, stream>>>(ctx, Wo_pk, bo, tmp, BL, D_, D_);
  ln_add_k<<<BL, 256, 0, stream>>>(tmp, dense, g1, b1ln, x1);

  gemm64_k<<<dim3(4, BL / 64), 256, 0, stream>>>(x1, W1_pk, b1f, h1, BL, D_, D_);
  final_k<<<N, 256, 0, stream>>>(h1, x1, gb, starts, g2, b2ln, (float*)d_out, Lmax);
}